// Round 1
// baseline (255.954 us; speedup 1.0000x reference)
//
#include <hip/hip_runtime.h>

#define VOCAB 50000
#define BROWS 4096
#define F 64
#define NCOLS 80            // 64 features + w_hi + w_lo + 14 zero pad
#define NT 5                // n-tiles of 16
#define SPLITS 16
#define KT_PER_SPLIT 98     // K-tiles (of 32) per split
#define KCHUNK (KT_PER_SPLIT * 32)        // 3136
#define KT_TOTAL (SPLITS * KT_PER_SPLIT)  // 1568
#define KPAD (KT_TOTAL * 32)              // 50176

typedef __attribute__((ext_vector_type(4))) float f32x4;
typedef __attribute__((ext_vector_type(8))) short s16x8;

__device__ __forceinline__ unsigned short f2bf(float f) {
    unsigned u = __builtin_bit_cast(unsigned, f);
    unsigned r = (u + 0x7FFFu + ((u >> 16) & 1u)) >> 16;   // round-to-nearest-even
    return (unsigned short)r;
}
__device__ __forceinline__ float bf2f(unsigned short b) {
    unsigned u = ((unsigned)b) << 16;
    return __builtin_bit_cast(float, u);
}

// --- kernel 1: w[k] = bias[k] - 0.5*||V[k]||^2 (0 for padded k) ---
__global__ void fm_prep_w(const float* __restrict__ V, const float* __restrict__ bias,
                          float* __restrict__ w) {
    int k = blockIdx.x * blockDim.x + threadIdx.x;
    if (k >= KPAD) return;
    float val = 0.f;
    if (k < VOCAB) {
        const float4* row = reinterpret_cast<const float4*>(V + (size_t)k * F);
        float ss = 0.f;
#pragma unroll
        for (int j = 0; j < F / 4; ++j) {
            float4 v = row[j];
            ss += v.x * v.x + v.y * v.y + v.z * v.z + v.w * v.w;
        }
        val = bias[k] - 0.5f * ss;
    }
    w[k] = val;
}

// --- kernel 2: pack B operand into MFMA 16x16x32 bf16 fragment order ---
// bfrag[(kt*NT + nt)*64 + lane] = uint4 of 8 bf16:
//   elem j = B[kt*32 + (lane>>4)*8 + j][nt*16 + (lane&15)]
// where B[k][n] = V[k][n] (n<64), w_hi[k] (n==64), w_lo[k] (n==65), 0 otherwise.
__global__ void fm_prep_bfrag(const float* __restrict__ V, const float* __restrict__ w,
                              uint4* __restrict__ bfrag) {
    int t = blockIdx.x * blockDim.x + threadIdx.x;
    if (t >= KT_TOTAL * NT * 64) return;
    int lane = t & 63;
    int tile = t >> 6;
    int nt = tile % NT;
    int kt = tile / NT;
    int n = nt * 16 + (lane & 15);
    int kbase = kt * 32 + (lane >> 4) * 8;
    unsigned short o[8];
#pragma unroll
    for (int j = 0; j < 8; ++j) {
        int k = kbase + j;
        float v = 0.f;
        if (k < VOCAB) {
            if (n < F) {
                v = V[(size_t)k * F + n];
            } else if (n == F) {
                v = w[k];                       // f2bf below -> w_hi
            } else if (n == F + 1) {
                float wv = w[k];
                v = wv - bf2f(f2bf(wv));        // residual -> w_lo
            }
        }
        o[j] = f2bf(v);
    }
    uint4 pk;
    pk.x = (unsigned)o[0] | ((unsigned)o[1] << 16);
    pk.y = (unsigned)o[2] | ((unsigned)o[3] << 16);
    pk.z = (unsigned)o[4] | ((unsigned)o[5] << 16);
    pk.w = (unsigned)o[6] | ((unsigned)o[7] << 16);
    bfrag[t] = pk;
}

// --- kernel 3: split-K MFMA GEMM, partials[split][row][col] f32 ---
__global__ __launch_bounds__(256, 4) void fm_main(const int* __restrict__ x,
                                                  const uint4* __restrict__ bfrag,
                                                  float* __restrict__ part) {
    int bx = blockIdx.x;
    int split = bx & (SPLITS - 1);
    int mblock = bx >> 4;
    int wave = threadIdx.x >> 6;
    int lane = threadIdx.x & 63;
    int kb = lane >> 4;                       // 0..3
    int rowA = mblock * 64 + wave * 16 + (lane & 15);
    const int* __restrict__ xrow = x + (size_t)rowA * VOCAB;

    f32x4 acc[NT];
#pragma unroll
    for (int nt = 0; nt < NT; ++nt) acc[nt] = (f32x4){0.f, 0.f, 0.f, 0.f};

    int kt0 = split * KT_PER_SPLIT;
    for (int it = 0; it < KT_PER_SPLIT; ++it) {
        int kt = kt0 + it;
        int k = kt * 32 + kb * 8;
        uint4 apk;
        if (k + 8 <= VOCAB) {
            int4 a0 = *reinterpret_cast<const int4*>(xrow + k);
            int4 a1 = *reinterpret_cast<const int4*>(xrow + k + 4);
            // x in {0,1}: bf16(1.0) = 0x3F80 ; pack two per dword
            apk.x = ((unsigned)a0.x + ((unsigned)a0.y << 16)) * 16256u;
            apk.y = ((unsigned)a0.z + ((unsigned)a0.w << 16)) * 16256u;
            apk.z = ((unsigned)a1.x + ((unsigned)a1.y << 16)) * 16256u;
            apk.w = ((unsigned)a1.z + ((unsigned)a1.w << 16)) * 16256u;
        } else {
            unsigned xv[8];
#pragma unroll
            for (int j = 0; j < 8; ++j) xv[j] = (k + j < VOCAB) ? (unsigned)xrow[k + j] : 0u;
            apk.x = (xv[0] + (xv[1] << 16)) * 16256u;
            apk.y = (xv[2] + (xv[3] << 16)) * 16256u;
            apk.z = (xv[4] + (xv[5] << 16)) * 16256u;
            apk.w = (xv[6] + (xv[7] << 16)) * 16256u;
        }
        s16x8 afrag = __builtin_bit_cast(s16x8, apk);
        const uint4* __restrict__ bbase = bfrag + (size_t)kt * (NT * 64) + lane;
#pragma unroll
        for (int nt = 0; nt < NT; ++nt) {
            s16x8 bf = __builtin_bit_cast(s16x8, bbase[nt * 64]);
            acc[nt] = __builtin_amdgcn_mfma_f32_16x16x32_bf16(afrag, bf, acc[nt], 0, 0, 0);
        }
    }

    // D layout: row = (lane>>4)*4 + r, col = lane&15 (within the 16x16 tile)
    float* __restrict__ p = part + (size_t)split * BROWS * NCOLS;
    int m0 = mblock * 64 + wave * 16 + kb * 4;
    int c0 = lane & 15;
#pragma unroll
    for (int nt = 0; nt < NT; ++nt)
#pragma unroll
        for (int r = 0; r < 4; ++r)
            p[(size_t)(m0 + r) * NCOLS + nt * 16 + c0] = acc[nt][r];
}

// --- kernel 4: reduce splits, square-sum, add linear term ---
__global__ void fm_reduce(const float* __restrict__ part, const float* __restrict__ gbias,
                          float* __restrict__ out) {
    int b = blockIdx.x * 4 + (threadIdx.x >> 6);
    int lane = threadIdx.x & 63;
    float acc = 0.f;
#pragma unroll
    for (int s = 0; s < SPLITS; ++s)
        acc += part[((size_t)s * BROWS + b) * NCOLS + lane];
    float sq = acc * acc;
    float ex = 0.f;
    if (lane < 16)       ex = part[((size_t)lane * BROWS + b) * NCOLS + F];
    else if (lane < 32)  ex = part[((size_t)(lane - 16) * BROWS + b) * NCOLS + F + 1];
#pragma unroll
    for (int off = 32; off; off >>= 1) {
        sq += __shfl_xor(sq, off, 64);
        ex += __shfl_xor(ex, off, 64);
    }
    if (lane == 0) out[b] = gbias[0] + ex + 0.5f * sq;
}

extern "C" void kernel_launch(void* const* d_in, const int* in_sizes, int n_in,
                              void* d_out, int out_size, void* d_ws, size_t ws_size,
                              hipStream_t stream) {
    const int*   x     = (const int*)d_in[0];
    const float* V     = (const float*)d_in[1];
    const float* bias  = (const float*)d_in[2];
    const float* gbias = (const float*)d_in[3];
    float* out = (float*)d_out;

    // workspace layout
    char* ws = (char*)d_ws;
    uint4* bfrag = (uint4*)ws;                                  // 8,028,160 B
    float* w     = (float*)(ws + (size_t)KT_TOTAL * NT * 64 * 16);
    float* part  = (float*)(ws + (size_t)KT_TOTAL * NT * 64 * 16 + (size_t)KPAD * 4);
    // total: 8,028,160 + 200,704 + 20,971,520 = 29,200,384 B

    fm_prep_w<<<(KPAD + 255) / 256, 256, 0, stream>>>(V, bias, w);
    fm_prep_bfrag<<<(KT_TOTAL * NT * 64 + 255) / 256, 256, 0, stream>>>(V, w, bfrag);
    fm_main<<<(BROWS / 64) * SPLITS, 256, 0, stream>>>(x, bfrag, part);
    fm_reduce<<<BROWS / 4, 256, 0, stream>>>(part, gbias, out);
}

// Round 2
// 201.605 us; speedup vs baseline: 1.2696x; 1.2696x over previous
//
#include <hip/hip_runtime.h>

#define VOCAB 50000
#define BROWS 4096
#define F 64
#define NCOLS 80            // 64 features + w_hi + w_lo + 14 zero pad
#define NT 5                // n-tiles of 16
#define SPLITS 16
#define KT_PER_SPLIT 98     // K-tiles (of 32) per split
#define KT_TOTAL (SPLITS * KT_PER_SPLIT)  // 1568
#define KPAD (KT_TOTAL * 32)              // 50176

#define AS1 __attribute__((address_space(1)))
#define AS3 __attribute__((address_space(3)))

typedef __attribute__((ext_vector_type(4))) float f32x4;
typedef __attribute__((ext_vector_type(8))) short s16x8;

__device__ __forceinline__ unsigned short f2bf(float f) {
    unsigned u = __builtin_bit_cast(unsigned, f);
    unsigned r = (u + 0x7FFFu + ((u >> 16) & 1u)) >> 16;   // round-to-nearest-even
    return (unsigned short)r;
}
__device__ __forceinline__ float bf2f(unsigned short b) {
    unsigned u = ((unsigned)b) << 16;
    return __builtin_bit_cast(float, u);
}

// --- kernel 1: w[k] = bias[k] - 0.5*||V[k]||^2 (0 for padded k) ---
__global__ void fm_prep_w(const float* __restrict__ V, const float* __restrict__ bias,
                          float* __restrict__ w) {
    int k = blockIdx.x * blockDim.x + threadIdx.x;
    if (k >= KPAD) return;
    float val = 0.f;
    if (k < VOCAB) {
        const float4* row = reinterpret_cast<const float4*>(V + (size_t)k * F);
        float ss = 0.f;
#pragma unroll
        for (int j = 0; j < F / 4; ++j) {
            float4 v = row[j];
            ss += v.x * v.x + v.y * v.y + v.z * v.z + v.w * v.w;
        }
        val = bias[k] - 0.5f * ss;
    }
    w[k] = val;
}

// --- kernel 2: pack B operand into MFMA 16x16x32 bf16 fragment order ---
// bfrag[(kt*NT + nt)*64 + lane] = uint4 of 8 bf16:
//   elem j = B[kt*32 + (lane>>4)*8 + j][nt*16 + (lane&15)]
// where B[k][n] = V[k][n] (n<64), w_hi[k] (n==64), w_lo[k] (n==65), 0 otherwise.
__global__ void fm_prep_bfrag(const float* __restrict__ V, const float* __restrict__ w,
                              uint4* __restrict__ bfrag) {
    int t = blockIdx.x * blockDim.x + threadIdx.x;
    if (t >= KT_TOTAL * NT * 64) return;
    int lane = t & 63;
    int tile = t >> 6;
    int nt = tile % NT;
    int kt = tile / NT;
    int n = nt * 16 + (lane & 15);
    int kbase = kt * 32 + (lane >> 4) * 8;
    unsigned short o[8];
#pragma unroll
    for (int j = 0; j < 8; ++j) {
        int k = kbase + j;
        float v = 0.f;
        if (k < VOCAB) {
            if (n < F) {
                v = V[(size_t)k * F + n];
            } else if (n == F) {
                v = w[k];                       // f2bf below -> w_hi
            } else if (n == F + 1) {
                float wv = w[k];
                v = wv - bf2f(f2bf(wv));        // residual -> w_lo
            }
        }
        o[j] = f2bf(v);
    }
    uint4 pk;
    pk.x = (unsigned)o[0] | ((unsigned)o[1] << 16);
    pk.y = (unsigned)o[2] | ((unsigned)o[3] << 16);
    pk.z = (unsigned)o[4] | ((unsigned)o[5] << 16);
    pk.w = (unsigned)o[6] | ((unsigned)o[7] << 16);
    bfrag[t] = pk;
}

// --- kernel 3: split-K MFMA GEMM with LDS-staged B (double-buffered) ---
__global__ __launch_bounds__(256, 4) void fm_main(const int* __restrict__ x,
                                                  const uint4* __restrict__ bfrag,
                                                  float* __restrict__ part) {
    __shared__ uint4 bbuf[2][NT * 64];        // 2 x 5120 B
    const int bx = blockIdx.x;
    const int split = bx & (SPLITS - 1);
    const int mblock = bx >> 4;
    const int tid = threadIdx.x;
    const int wave = tid >> 6;
    const int lane = tid & 63;
    const int kb = lane >> 4;                 // 0..3
    const int rowA = mblock * 64 + wave * 16 + (lane & 15);
    const int* __restrict__ xrow = x + (size_t)rowA * VOCAB;
    const int kt0 = split * KT_PER_SPLIT;

    auto stage = [&](int buf, int kt) {
        const uint4* src = bfrag + (size_t)kt * (NT * 64);
        // wave w stages fragment elems [w*64, w*64+64); lane offset is implicit (+lane*16)
        __builtin_amdgcn_global_load_lds(
            (const AS1 void*)(src + (wave << 6) + lane),
            (AS3 void*)(&bbuf[buf][wave << 6]), 16, 0, 0);
        if (wave == 0)                        // elems 256..319
            __builtin_amdgcn_global_load_lds(
                (const AS1 void*)(src + 256 + lane),
                (AS3 void*)(&bbuf[buf][256]), 16, 0, 0);
    };

    f32x4 acc[NT];
#pragma unroll
    for (int nt = 0; nt < NT; ++nt) acc[nt] = (f32x4){0.f, 0.f, 0.f, 0.f};

    stage(0, kt0);
    __syncthreads();
    int cur = 0;

    // first K-tile needing a bounds check: kt >= 1562
    const int nfull = (split == SPLITS - 1) ? (((VOCAB - 32) >> 5) + 1 - kt0) : KT_PER_SPLIT;

    int it = 0;
    for (; it < nfull; ++it) {                // unguarded fast path
        if (it + 1 < KT_PER_SPLIT) stage(cur ^ 1, kt0 + it + 1);
        const int k = (kt0 + it) * 32 + kb * 8;
        int4 a0 = *reinterpret_cast<const int4*>(xrow + k);
        int4 a1 = *reinterpret_cast<const int4*>(xrow + k + 4);
        uint4 apk;                            // x in {0,1}: bf16(1.0) = 0x3F80
        apk.x = ((unsigned)a0.x + ((unsigned)a0.y << 16)) * 16256u;
        apk.y = ((unsigned)a0.z + ((unsigned)a0.w << 16)) * 16256u;
        apk.z = ((unsigned)a1.x + ((unsigned)a1.y << 16)) * 16256u;
        apk.w = ((unsigned)a1.z + ((unsigned)a1.w << 16)) * 16256u;
        s16x8 afrag = __builtin_bit_cast(s16x8, apk);
#pragma unroll
        for (int nt = 0; nt < NT; ++nt) {
            s16x8 bf = __builtin_bit_cast(s16x8, bbuf[cur][nt * 64 + lane]);
            acc[nt] = __builtin_amdgcn_mfma_f32_16x16x32_bf16(afrag, bf, acc[nt], 0, 0, 0);
        }
        __syncthreads();
        cur ^= 1;
    }
    for (; it < KT_PER_SPLIT; ++it) {         // guarded tail (last 6 tiles of split 15)
        if (it + 1 < KT_PER_SPLIT) stage(cur ^ 1, kt0 + it + 1);
        const int k = (kt0 + it) * 32 + kb * 8;
        unsigned xv[8];
#pragma unroll
        for (int j = 0; j < 8; ++j) xv[j] = (k + j < VOCAB) ? (unsigned)xrow[k + j] : 0u;
        uint4 apk;
        apk.x = (xv[0] + (xv[1] << 16)) * 16256u;
        apk.y = (xv[2] + (xv[3] << 16)) * 16256u;
        apk.z = (xv[4] + (xv[5] << 16)) * 16256u;
        apk.w = (xv[6] + (xv[7] << 16)) * 16256u;
        s16x8 afrag = __builtin_bit_cast(s16x8, apk);
#pragma unroll
        for (int nt = 0; nt < NT; ++nt) {
            s16x8 bf = __builtin_bit_cast(s16x8, bbuf[cur][nt * 64 + lane]);
            acc[nt] = __builtin_amdgcn_mfma_f32_16x16x32_bf16(afrag, bf, acc[nt], 0, 0, 0);
        }
        __syncthreads();
        cur ^= 1;
    }

    // D layout: row = (lane>>4)*4 + r, col = lane&15 (within the 16x16 tile)
    float* __restrict__ p = part + (size_t)split * BROWS * NCOLS;
    int m0 = mblock * 64 + wave * 16 + kb * 4;
    int c0 = lane & 15;
#pragma unroll
    for (int nt = 0; nt < NT; ++nt)
#pragma unroll
        for (int r = 0; r < 4; ++r)
            p[(size_t)(m0 + r) * NCOLS + nt * 16 + c0] = acc[nt][r];
}

// --- kernel 4: reduce splits, square-sum, add linear term ---
__global__ void fm_reduce(const float* __restrict__ part, const float* __restrict__ gbias,
                          float* __restrict__ out) {
    int b = blockIdx.x * 4 + (threadIdx.x >> 6);
    int lane = threadIdx.x & 63;
    float acc = 0.f;
#pragma unroll
    for (int s = 0; s < SPLITS; ++s)
        acc += part[((size_t)s * BROWS + b) * NCOLS + lane];
    float sq = acc * acc;
    float ex = 0.f;
    if (lane < 16)       ex = part[((size_t)lane * BROWS + b) * NCOLS + F];
    else if (lane < 32)  ex = part[((size_t)(lane - 16) * BROWS + b) * NCOLS + F + 1];
#pragma unroll
    for (int off = 32; off; off >>= 1) {
        sq += __shfl_xor(sq, off, 64);
        ex += __shfl_xor(ex, off, 64);
    }
    if (lane == 0) out[b] = gbias[0] + ex + 0.5f * sq;
}

extern "C" void kernel_launch(void* const* d_in, const int* in_sizes, int n_in,
                              void* d_out, int out_size, void* d_ws, size_t ws_size,
                              hipStream_t stream) {
    const int*   x     = (const int*)d_in[0];
    const float* V     = (const float*)d_in[1];
    const float* bias  = (const float*)d_in[2];
    const float* gbias = (const float*)d_in[3];
    float* out = (float*)d_out;

    // workspace layout
    char* ws = (char*)d_ws;
    uint4* bfrag = (uint4*)ws;                                  // 8,028,160 B
    float* w     = (float*)(ws + (size_t)KT_TOTAL * NT * 64 * 16);
    float* part  = (float*)(ws + (size_t)KT_TOTAL * NT * 64 * 16 + (size_t)KPAD * 4);
    // total: 8,028,160 + 200,704 + 20,971,520 = 29,200,384 B

    fm_prep_w<<<(KPAD + 255) / 256, 256, 0, stream>>>(V, bias, w);
    fm_prep_bfrag<<<(KT_TOTAL * NT * 64 + 255) / 256, 256, 0, stream>>>(V, w, bfrag);
    fm_main<<<(BROWS / 64) * SPLITS, 256, 0, stream>>>(x, bfrag, part);
    fm_reduce<<<BROWS / 4, 256, 0, stream>>>(part, gbias, out);
}